// Round 10
// baseline (702.950 us; speedup 1.0000x reference)
//
#include <hip/hip_runtime.h>
#include <hip/hip_bf16.h>
#include <math.h>

#define NT 50000
#define NP 256
#define NE 800000
#define ET 850000   // NE + NT self loops
#define EMBD 64
#define NHEADS 4
#define HE 256      // NHEADS*EMBD
#define NG 8
#define NBLK 49     // scan blocks of 1024

typedef __attribute__((ext_vector_type(8))) short bf16x8;
typedef __attribute__((ext_vector_type(4))) float f32x4;

// ---- workspace layout (bytes) ----
#define OFF_DEG    0u           // 50000 i32
#define OFF_INDPTR 200192u      // 50001 i32
#define OFF_CURSOR 400384u      // 50000 i32
#define OFF_BLKSUM 600576u      // 64 i32
#define OFF_MG     600832u      // 96 f32
#define OFF_MH     601216u      // 12 f32
#define OFF_MEAN   601280u      // 8 f32            <- memset zone start
#define OFF_TPSUM  601344u      // 512 f32
#define OFF_TPCNT  603392u      // 8 f32            <- memset zone end (2144 B)
#define OFF_ER0    603648u      // 850000 uint4 {src, ae01, ae23, 0}
#define OFF_ER1    14203648u
#define OFF_ER2    27803648u
#define OFF_ASRC   41403648u    // 50048*4 f32
#define OFF_ADST   42204416u
#define OFF_HT     43005184u    // 50048*64 f32
#define OFF_XL     55817472u    // 50000*256 bf16
#define OFF_AGG    81417472u    // 50048*256 bf16
#define OFF_WXF    107042048u   // 3*16384 bf16
#define OFF_WPF    107140352u   // 3*16384 bf16
#define OFF_WSD    107238656u   // 3*1024 bf16 (a_src/a_dst MFMA B-tiles)
// total ~107.3 MB

__device__ __forceinline__ float bf_lo(unsigned int u) {
  union { unsigned int i; float f; } v; v.i = u << 16; return v.f;
}
__device__ __forceinline__ float bf_hi(unsigned int u) {
  union { unsigned int i; float f; } v; v.i = u & 0xffff0000u; return v.f;
}
__device__ __forceinline__ unsigned pk2(float a, float b) {
  unsigned ua = __bfloat16_as_ushort(__float2bfloat16(a));
  unsigned ub = __bfloat16_as_ushort(__float2bfloat16(b));
  return ua | (ub << 16);
}

// ---------------- degree + edge_attr mean (fused) ----------------
__global__ __launch_bounds__(256) void k_degree_mean(const int* __restrict__ ei1,
    const float* __restrict__ ea, int* __restrict__ deg, float* __restrict__ sums) {
  __shared__ float lds[256];
  int tid = threadIdx.x;
  int e = blockIdx.x * 256 + tid;
  if (e < ET) {
    int d = (e < NE) ? ei1[e] : (e - NE);
    atomicAdd(&deg[d], 1);
  }
  int k = tid & 7, rl = tid >> 3;
  float s = 0.f;
  for (int row = blockIdx.x * 32 + rl; row < NE; row += gridDim.x * 32)
    s += ea[(size_t)row * 8 + k];
  lds[tid] = s;
  __syncthreads();
  for (int off = 128; off >= 8; off >>= 1) {
    if (tid < off) lds[tid] += lds[tid + off];
    __syncthreads();
  }
  if (tid < 8) atomicAdd(&sums[tid], lds[tid]);
}

// ---------------- parallel scan (2 kernels) ----------------
__global__ __launch_bounds__(1024) void k_scanA(const int* __restrict__ deg,
    int* __restrict__ indptr, int* __restrict__ blksum) {
  __shared__ int wsum[16];
  int tid = threadIdx.x, lane = tid & 63, wid = tid >> 6;
  int i = blockIdx.x * 1024 + tid;
  int v = (i < NT) ? deg[i] : 0;
  int x = v;
  #pragma unroll
  for (int off = 1; off < 64; off <<= 1) {
    int t = __shfl_up(x, off, 64);
    if (lane >= off) x += t;
  }
  if (lane == 63) wsum[wid] = x;
  __syncthreads();
  if (wid == 0 && lane < 16) {
    int w = wsum[lane];
    #pragma unroll
    for (int off = 1; off < 16; off <<= 1) {
      int t = __shfl_up(w, off, 64);
      if (lane >= off) w += t;
    }
    wsum[lane] = w;  // inclusive
  }
  __syncthreads();
  int woff = (wid == 0) ? 0 : wsum[wid - 1];
  if (i < NT) indptr[i] = x + woff - v;   // block-local exclusive
  if (tid == 1023) blksum[blockIdx.x] = wsum[15];
}

__global__ __launch_bounds__(1024) void k_scanB(const int* __restrict__ blksum,
    int* __restrict__ indptr, int* __restrict__ cursor) {
  __shared__ int bs[NBLK];
  int tid = threadIdx.x;
  if (tid < NBLK) bs[tid] = blksum[tid];
  __syncthreads();
  int off = 0;
  for (int j = 0; j < (int)blockIdx.x; j++) off += bs[j];
  int i = blockIdx.x * 1024 + tid;
  if (i < NT) {
    int e = indptr[i] + off;
    indptr[i] = e;
    cursor[i] = e;
  }
  if (blockIdx.x == 0 && tid == 0) {
    int tot = 0;
    for (int j = 0; j < NBLK; j++) tot += bs[j];
    indptr[NT] = tot;
  }
}

// ---------------- M matrices + wsd tiles (all 3 layers) ----------------
__global__ __launch_bounds__(256) void k_mprep(const float* __restrict__ We,
    const float* __restrict__ ae, const float* __restrict__ msum,
    const float* __restrict__ Wx, const float* __restrict__ as_all,
    const float* __restrict__ ad_all,
    float* __restrict__ Mg, float* __restrict__ Mh, __hip_bfloat16* __restrict__ wsd) {
  int t = threadIdx.x;
  if (t < 96) {
    int l = t >> 5, idx = t & 31, k = idx >> 2, h = idx & 3;
    const float* Wl = We + (size_t)l * 8 * HE;
    const float* al = ae + (size_t)l * NHEADS * EMBD;
    float s = 0.f;
    #pragma unroll
    for (int d = 0; d < 64; d++) s += Wl[k * HE + h * 64 + d] * al[h * 64 + d];
    Mg[t] = s;
  }
  __syncthreads();
  if (t < 12) {
    int l = t >> 2, h = t & 3;
    float m = 0.f;
    #pragma unroll
    for (int k = 0; k < 8; k++) m += msum[k] * (1.f / NE) * Mg[l * 32 + k * 4 + h];
    Mh[t] = m;
  }
  for (int v = t; v < 3072; v += 256) {
    int l = v >> 10, rem = v & 1023;
    int kb = rem >> 9, rem2 = rem & 511;
    int lane = rem2 >> 3, j = rem2 & 7;
    int quad = lane >> 4, l15 = lane & 15;
    int k = kb * 32 + quad * 8 + j;
    float val = 0.f;
    if (l15 < 8) {
      int h = l15 & 3;
      const float* av = ((l15 < 4) ? as_all : ad_all) + (size_t)l * NHEADS * EMBD + h * 64;
      const float* Wr = Wx + (size_t)l * 64 * 256 + (size_t)k * 256 + h * 64;
      #pragma unroll
      for (int d = 0; d < 64; d++) val += Wr[d] * av[d];
    }
    wsd[(size_t)l * 1024 + (size_t)(kb * 64 + lane) * 8 + j] = __float2bfloat16(val);
  }
}

// ---------------- CSR fill: packed per-layer records {src, aeh bf16 x4} ----------------
__global__ __launch_bounds__(256) void k_fill(const int* __restrict__ ei0,
    const int* __restrict__ ei1, const float* __restrict__ ea,
    const float* __restrict__ Mg, const float* __restrict__ Mh,
    int* __restrict__ cursor,
    uint4* __restrict__ er0, uint4* __restrict__ er1, uint4* __restrict__ er2) {
  __shared__ float MgS[96];
  __shared__ float MhS[12];
  int t = threadIdx.x;
  if (t < 96) MgS[t] = Mg[t];
  if (t < 12) MhS[t] = Mh[t];
  __syncthreads();
  int e = blockIdx.x * 256 + t;
  if (e >= ET) return;
  int d, s;
  float r[3][4];
  if (e < NE) {
    d = ei1[e]; s = ei0[e];
    const float4* pp = (const float4*)(ea + (size_t)e * 8);
    float4 v0 = pp[0], v1 = pp[1];
    float v[8] = {v0.x, v0.y, v0.z, v0.w, v1.x, v1.y, v1.z, v1.w};
    #pragma unroll
    for (int l = 0; l < 3; l++) {
      #pragma unroll
      for (int h = 0; h < 4; h++) {
        float acc = 0.f;
        #pragma unroll
        for (int k = 0; k < 8; k++) acc += v[k] * MgS[l * 32 + k * 4 + h];
        r[l][h] = acc;
      }
    }
  } else {
    d = e - NE; s = d;
    #pragma unroll
    for (int l = 0; l < 3; l++)
      #pragma unroll
      for (int h = 0; h < 4; h++) r[l][h] = MhS[l * 4 + h];
  }
  int p = atomicAdd(&cursor[d], 1);
  uint4 rc;
  rc.x = (unsigned)s; rc.w = 0u;
  rc.y = pk2(r[0][0], r[0][1]); rc.z = pk2(r[0][2], r[0][3]); er0[p] = rc;
  rc.y = pk2(r[1][0], r[1][1]); rc.z = pk2(r[1][2], r[1][3]); er1[p] = rc;
  rc.y = pk2(r[2][0], r[2][1]); rc.z = pk2(r[2][2], r[2][3]); er2[p] = rc;
}

// ---------------- weight fragment prep (fused xl+proj) ----------------
__global__ void k_prep_w(const float* __restrict__ Wx, const float* __restrict__ Wp,
                         __hip_bfloat16* __restrict__ Wxf, __hip_bfloat16* __restrict__ Wpf) {
  int lane = threadIdx.x;
  int bid = blockIdx.x;
  int quad = lane >> 4, l15 = lane & 15;
  if (bid < 96) {
    int l = bid >> 5, rem = bid & 31, t = rem >> 1, kb = rem & 1;
    const float* Wl = Wx + (size_t)l * 64 * 256;
    __hip_bfloat16* out = Wxf + (size_t)l * 16384 + (size_t)((t * 2 + kb) * 64 + lane) * 8;
    #pragma unroll
    for (int j = 0; j < 8; j++)
      out[j] = __float2bfloat16(Wl[(kb * 32 + quad * 8 + j) * 256 + t * 16 + l15]);
  } else {
    bid -= 96;
    int l = bid >> 5, rem = bid & 31, t = rem >> 3, kb = rem & 7;
    const float* Wl = Wp + (size_t)l * 256 * 64;
    __hip_bfloat16* out = Wpf + (size_t)l * 16384 + (size_t)((t * 8 + kb) * 64 + lane) * 8;
    #pragma unroll
    for (int j = 0; j < 8; j++)
      out[j] = __float2bfloat16(Wl[(kb * 32 + quad * 8 + j) * 64 + t * 16 + l15]);
  }
}

// ---------------- fused embed + xl(0) + a_src/a_dst(0) ----------------
__global__ __launch_bounds__(256) void k_embed_xl(const float* __restrict__ x,
    const float* __restrict__ W, const float* __restrict__ b,
    const __hip_bfloat16* __restrict__ Wf, const __hip_bfloat16* __restrict__ wsd,
    float* __restrict__ ht, __hip_bfloat16* __restrict__ xl,
    float* __restrict__ a_src, float* __restrict__ a_dst) {
  __shared__ __hip_bfloat16 hbuf[64 * 72];
  __shared__ __hip_bfloat16 cb16[64 * 264];
  int tid = threadIdx.x, lane = tid & 63, wave = tid >> 6;
  int quad = lane >> 4, l15 = lane & 15;
  int r0 = blockIdx.x * 64;
  {
    float breg[16];
    #pragma unroll
    for (int k = 0; k < 16; k++) breg[k] = W[k * 64 + lane];
    float bias = b[lane];
    #pragma unroll 1
    for (int rr = 0; rr < 16; rr++) {
      int row = r0 + wave * 16 + rr;
      float acc = bias;
      if (row < NT) {
        const float4* xr = (const float4*)(x + (size_t)row * 16);
        #pragma unroll
        for (int q = 0; q < 4; q++) {
          float4 v = xr[q];
          acc += v.x * breg[q*4+0] + v.y * breg[q*4+1] + v.z * breg[q*4+2] + v.w * breg[q*4+3];
        }
        ht[(size_t)row * 64 + lane] = acc;
      }
      hbuf[(wave * 16 + rr) * 72 + lane] = __float2bfloat16(acc);
    }
  }
  __syncthreads();
  f32x4 acc[16], accE;
  #pragma unroll
  for (int t = 0; t < 16; t++) acc[t] = (f32x4){0.f, 0.f, 0.f, 0.f};
  accE = (f32x4){0.f, 0.f, 0.f, 0.f};
  #pragma unroll
  for (int kb = 0; kb < 2; kb++) {
    bf16x8 a = *(const bf16x8*)(&hbuf[(wave * 16 + l15) * 72 + kb * 32 + quad * 8]);
    #pragma unroll
    for (int t = 0; t < 16; t++) {
      bf16x8 bfr = *(const bf16x8*)(Wf + (size_t)((t * 2 + kb) * 64 + lane) * 8);
      acc[t] = __builtin_amdgcn_mfma_f32_16x16x32_bf16(a, bfr, acc[t], 0, 0, 0);
    }
    bf16x8 bs = *(const bf16x8*)(wsd + (size_t)(kb * 64 + lane) * 8);
    accE = __builtin_amdgcn_mfma_f32_16x16x32_bf16(a, bs, accE, 0, 0, 0);
  }
  int rloc = wave * 16 + quad * 4;
  #pragma unroll
  for (int t = 0; t < 16; t++) {
    #pragma unroll
    for (int reg = 0; reg < 4; reg++)
      cb16[(rloc + reg) * 264 + t * 16 + l15] = __float2bfloat16(acc[t][reg]);
  }
  #pragma unroll
  for (int reg = 0; reg < 4; reg++) {
    int row = r0 + rloc + reg;
    if (l15 < 8 && row < NT) {
      float* dst = (l15 < 4) ? a_src : a_dst;
      dst[row * 4 + (l15 & 3)] = accE[reg];
    }
  }
  __syncthreads();
  #pragma unroll
  for (int k = 0; k < 8; k++) {
    int c = k * 256 + tid;
    int row = c >> 5, off = c & 31;
    if (r0 + row < NT) {
      uint4 v = *(const uint4*)(&cb16[row * 264 + off * 8]);
      *(uint4*)(xl + (size_t)(r0 + row) * HE + off * 8) = v;
    }
  }
}

// ---------------- fused softmax + aggregate (no-max softmax, batched gathers) ----------------
__global__ __launch_bounds__(256) void k_attn(
    const __hip_bfloat16* __restrict__ xl, const float* __restrict__ a_src,
    const float* __restrict__ a_dst, const uint4* __restrict__ er,
    const int* __restrict__ indptr, const float* __restrict__ gb,
    __hip_bfloat16* __restrict__ agg) {
  int node = blockIdx.x * 4 + (threadIdx.x >> 6);
  int lane = threadIdx.x & 63;
  int h = lane >> 4;
  int hbase = lane & 48;
  int e15 = lane & 15;
  int beg = indptr[node], end = indptr[node + 1];
  float adh = a_dst[node * 4 + h];
  float S = 0.f;
  float acc0 = 0.f, acc1 = 0.f, acc2 = 0.f, acc3 = 0.f;
  for (int base = beg; base < end; base += 16) {
    int cnt = end - base;           // >=1
    bool ok = e15 < cnt;
    uint4 rec; rec.x = 0u; rec.y = 0u; rec.z = 0u; rec.w = 0u;
    if (ok) rec = er[base + e15];
    int my_src = (int)rec.x;
    unsigned wsel = (h < 2) ? rec.y : rec.z;
    float aeh = (h & 1) ? bf_hi(wsel) : bf_lo(wsel);
    float asr = ok ? a_src[(size_t)my_src * 4 + h] : 0.f;
    float al = asr + adh + aeh;
    al = (al > 0.f) ? al : 0.2f * al;
    float ex = ok ? __expf(al) : 0.f;   // no max-shift: al bounded (see analysis)
    S += ex;
    #pragma unroll
    for (int jb = 0; jb < 2; jb++) {
      int sr[8];
      #pragma unroll
      for (int j = 0; j < 8; j++) sr[j] = __shfl(my_src, jb * 8 + j, 64);
      uint2 u[8];
      #pragma unroll
      for (int j = 0; j < 8; j++)
        u[j] = *(const uint2*)(xl + (size_t)sr[j] * HE + lane * 4);
      #pragma unroll
      for (int j = 0; j < 8; j++) {
        float cf = __shfl(ex, hbase | (jb * 8 + j), 64);
        acc0 += cf * bf_lo(u[j].x);
        acc1 += cf * bf_hi(u[j].x);
        acc2 += cf * bf_lo(u[j].y);
        acc3 += cf * bf_hi(u[j].y);
      }
    }
  }
  #pragma unroll
  for (int off = 1; off < 16; off <<= 1) S += __shfl_xor(S, off, 64);
  float inv = 1.f / (S + 1e-16f);
  float4 g4 = *(const float4*)(gb + lane * 4);
  unsigned int o0 = __bfloat16_as_ushort(__float2bfloat16(acc0 * inv + g4.x));
  unsigned int o1 = __bfloat16_as_ushort(__float2bfloat16(acc1 * inv + g4.y));
  unsigned int o2 = __bfloat16_as_ushort(__float2bfloat16(acc2 * inv + g4.z));
  unsigned int o3 = __bfloat16_as_ushort(__float2bfloat16(acc3 * inv + g4.w));
  uint2 out; out.x = o0 | (o1 << 16); out.y = o2 | (o3 << 16);
  *(uint2*)(agg + (size_t)node * HE + lane * 4) = out;
}

// ---------------- fused proj + LN + next-layer xl + a_src/a_dst ----------------
__global__ __launch_bounds__(256) void k_proj_xl(
    const __hip_bfloat16* __restrict__ agg, const __hip_bfloat16* __restrict__ Wpf,
    const float* __restrict__ pb, const float* __restrict__ g, const float* __restrict__ bln,
    const float* __restrict__ ht_io,
    const __hip_bfloat16* __restrict__ Wxf, const __hip_bfloat16* __restrict__ wsd,
    float* __restrict__ ht_out, __hip_bfloat16* __restrict__ xl,
    float* __restrict__ a_src, float* __restrict__ a_dst) {
  __shared__ __hip_bfloat16 cb16[64 * 264];   // also used as f32 cbuf (pitch 68)
  __shared__ __hip_bfloat16 hbuf[64 * 72];
  __shared__ float pbL[64], gL[64], bL[64];
  float* cbf = (float*)cb16;
  int tid = threadIdx.x, lane = tid & 63, wave = tid >> 6;
  int quad = lane >> 4, l15 = lane & 15;
  if (tid < 64) { pbL[tid] = pb[tid]; gL[tid] = g[tid]; bL[tid] = bln[tid]; }
  int r0 = blockIdx.x * 64;
  int arow = r0 + wave * 16 + l15;
  {
    f32x4 pacc[4];
    #pragma unroll
    for (int t = 0; t < 4; t++) pacc[t] = (f32x4){0.f, 0.f, 0.f, 0.f};
    #pragma unroll
    for (int kb = 0; kb < 8; kb++) {
      bf16x8 a = *(const bf16x8*)(agg + (size_t)arow * HE + kb * 32 + quad * 8);
      #pragma unroll
      for (int t = 0; t < 4; t++) {
        bf16x8 bfr = *(const bf16x8*)(Wpf + (size_t)((t * 8 + kb) * 64 + lane) * 8);
        pacc[t] = __builtin_amdgcn_mfma_f32_16x16x32_bf16(a, bfr, pacc[t], 0, 0, 0);
      }
    }
    int rloc = wave * 16 + quad * 4;
    #pragma unroll
    for (int t = 0; t < 4; t++) {
      #pragma unroll
      for (int reg = 0; reg < 4; reg++)
        cbf[(rloc + reg) * 68 + t * 16 + l15] = pacc[t][reg];
    }
  }
  __syncthreads();
  {
    int r = tid >> 2, q = tid & 3;
    int row = r0 + r;
    float h[16], s1 = 0.f, s2 = 0.f;
    const float* hin = ht_io + (size_t)row * 64 + q * 16;
    #pragma unroll
    for (int d = 0; d < 16; d++) {
      float u = cbf[r * 68 + q * 16 + d] + pbL[q * 16 + d];
      u = (u > 0.f) ? u : (__expf(u) - 1.f);
      float hv = hin[d] + u;
      h[d] = hv;
      s1 += hv; s2 += hv * hv;
    }
    s1 += __shfl_xor(s1, 1, 64); s1 += __shfl_xor(s1, 2, 64);
    s2 += __shfl_xor(s2, 1, 64); s2 += __shfl_xor(s2, 2, 64);
    float mu = s1 * 0.015625f;
    float var = s2 * 0.015625f - mu * mu;
    float rstd = rsqrtf(var + 1e-5f);
    float o[16];
    #pragma unroll
    for (int d = 0; d < 16; d++)
      o[d] = (h[d] - mu) * rstd * gL[q * 16 + d] + bL[q * 16 + d];
    if (row < NT) {
      float* outp = ht_out + (size_t)row * 64 + q * 16;
      #pragma unroll
      for (int d4 = 0; d4 < 4; d4++) {
        float4 v; v.x = o[d4*4]; v.y = o[d4*4+1]; v.z = o[d4*4+2]; v.w = o[d4*4+3];
        *(float4*)(outp + d4 * 4) = v;
      }
    }
    uint4 u0, u1;
    u0.x = pk2(o[0], o[1]);  u0.y = pk2(o[2], o[3]);
    u0.z = pk2(o[4], o[5]);  u0.w = pk2(o[6], o[7]);
    u1.x = pk2(o[8], o[9]);  u1.y = pk2(o[10], o[11]);
    u1.z = pk2(o[12], o[13]); u1.w = pk2(o[14], o[15]);
    uint4* hb = (uint4*)(&hbuf[r * 72 + q * 16]);
    hb[0] = u0; hb[1] = u1;
  }
  __syncthreads();
  f32x4 acc[16], accE;
  #pragma unroll
  for (int t = 0; t < 16; t++) acc[t] = (f32x4){0.f, 0.f, 0.f, 0.f};
  accE = (f32x4){0.f, 0.f, 0.f, 0.f};
  #pragma unroll
  for (int kb = 0; kb < 2; kb++) {
    bf16x8 a = *(const bf16x8*)(&hbuf[(wave * 16 + l15) * 72 + kb * 32 + quad * 8]);
    #pragma unroll
    for (int t = 0; t < 16; t++) {
      bf16x8 bfr = *(const bf16x8*)(Wxf + (size_t)((t * 2 + kb) * 64 + lane) * 8);
      acc[t] = __builtin_amdgcn_mfma_f32_16x16x32_bf16(a, bfr, acc[t], 0, 0, 0);
    }
    bf16x8 bs = *(const bf16x8*)(wsd + (size_t)(kb * 64 + lane) * 8);
    accE = __builtin_amdgcn_mfma_f32_16x16x32_bf16(a, bs, accE, 0, 0, 0);
  }
  int rloc = wave * 16 + quad * 4;
  #pragma unroll
  for (int t = 0; t < 16; t++) {
    #pragma unroll
    for (int reg = 0; reg < 4; reg++)
      cb16[(rloc + reg) * 264 + t * 16 + l15] = __float2bfloat16(acc[t][reg]);
  }
  #pragma unroll
  for (int reg = 0; reg < 4; reg++) {
    int row = r0 + rloc + reg;
    if (l15 < 8 && row < NT) {
      float* dst = (l15 < 4) ? a_src : a_dst;
      dst[row * 4 + (l15 & 3)] = accE[reg];
    }
  }
  __syncthreads();
  #pragma unroll
  for (int k = 0; k < 8; k++) {
    int c = k * 256 + tid;
    int row = c >> 5, off = c & 31;
    if (r0 + row < NT) {
      uint4 v = *(const uint4*)(&cb16[row * 264 + off * 8]);
      *(uint4*)(xl + (size_t)(r0 + row) * HE + off * 8) = v;
    }
  }
}

// ---------------- last-layer proj + LN (writes out_ht only) ----------------
__global__ __launch_bounds__(256) void k_proj_last(
    const __hip_bfloat16* __restrict__ agg, const __hip_bfloat16* __restrict__ Wpf,
    const float* __restrict__ pb, const float* __restrict__ g, const float* __restrict__ bln,
    const float* __restrict__ ht_in, float* __restrict__ ht_out) {
  __shared__ float cbf[64 * 68];
  __shared__ float pbL[64], gL[64], bL[64];
  int tid = threadIdx.x, lane = tid & 63, wave = tid >> 6;
  int quad = lane >> 4, l15 = lane & 15;
  if (tid < 64) { pbL[tid] = pb[tid]; gL[tid] = g[tid]; bL[tid] = bln[tid]; }
  int r0 = blockIdx.x * 64;
  int arow = r0 + wave * 16 + l15;
  f32x4 pacc[4];
  #pragma unroll
  for (int t = 0; t < 4; t++) pacc[t] = (f32x4){0.f, 0.f, 0.f, 0.f};
  #pragma unroll
  for (int kb = 0; kb < 8; kb++) {
    bf16x8 a = *(const bf16x8*)(agg + (size_t)arow * HE + kb * 32 + quad * 8);
    #pragma unroll
    for (int t = 0; t < 4; t++) {
      bf16x8 bfr = *(const bf16x8*)(Wpf + (size_t)((t * 8 + kb) * 64 + lane) * 8);
      pacc[t] = __builtin_amdgcn_mfma_f32_16x16x32_bf16(a, bfr, pacc[t], 0, 0, 0);
    }
  }
  int rloc = wave * 16 + quad * 4;
  #pragma unroll
  for (int t = 0; t < 4; t++) {
    #pragma unroll
    for (int reg = 0; reg < 4; reg++)
      cbf[(rloc + reg) * 68 + t * 16 + l15] = pacc[t][reg];
  }
  __syncthreads();
  int r = tid >> 2, q = tid & 3;
  int row = r0 + r;
  float h[16], s1 = 0.f, s2 = 0.f;
  const float* hin = ht_in + (size_t)row * 64 + q * 16;
  #pragma unroll
  for (int d = 0; d < 16; d++) {
    float u = cbf[r * 68 + q * 16 + d] + pbL[q * 16 + d];
    u = (u > 0.f) ? u : (__expf(u) - 1.f);
    float hv = hin[d] + u;
    h[d] = hv;
    s1 += hv; s2 += hv * hv;
  }
  s1 += __shfl_xor(s1, 1, 64); s1 += __shfl_xor(s1, 2, 64);
  s2 += __shfl_xor(s2, 1, 64); s2 += __shfl_xor(s2, 2, 64);
  float mu = s1 * 0.015625f;
  float var = s2 * 0.015625f - mu * mu;
  float rstd = rsqrtf(var + 1e-5f);
  if (row < NT) {
    float* outp = ht_out + (size_t)row * 64 + q * 16;
    #pragma unroll
    for (int d4 = 0; d4 < 4; d4++) {
      float4 v;
      v.x = (h[d4*4+0] - mu) * rstd * gL[q*16+d4*4+0] + bL[q*16+d4*4+0];
      v.y = (h[d4*4+1] - mu) * rstd * gL[q*16+d4*4+1] + bL[q*16+d4*4+1];
      v.z = (h[d4*4+2] - mu) * rstd * gL[q*16+d4*4+2] + bL[q*16+d4*4+2];
      v.w = (h[d4*4+3] - mu) * rstd * gL[q*16+d4*4+3] + bL[q*16+d4*4+3];
      *(float4*)(outp + d4 * 4) = v;
    }
  }
}

// ---------------- task head + fused mean-pool ----------------
__global__ __launch_bounds__(256) void k_task_head(const float* __restrict__ ht,
    const int* __restrict__ tb,
    const float* __restrict__ W1, const float* __restrict__ b1,
    const float* __restrict__ W2, const float* __restrict__ b2,
    float* __restrict__ logits, float* __restrict__ sums, float* __restrict__ cnt) {
  __shared__ float lh[8 * 64];
  int t = threadIdx.x;
  int row0 = blockIdx.x * 8;
  size_t base = (size_t)row0 * 64;
  lh[t] = ht[base + t];
  lh[t + 256] = ht[base + t + 256];
  __syncthreads();
  int i = t >> 5, j = t & 31;
  float s = b1[j];
  #pragma unroll 8
  for (int d = 0; d < 64; d++) s += lh[i * 64 + d] * W1[d * 32 + j];
  s = fmaxf(s, 0.f);
  float p = s * W2[j];
  #pragma unroll
  for (int off = 16; off; off >>= 1) p += __shfl_xor(p, off, 64);
  if (j == 0) logits[row0 + i] = p + b2[0];
  // fused mean-pool partials (tbatch sorted -> usually one group per block)
  if (t < 64) {
    int g0 = tb[row0], g7 = tb[row0 + 7];
    if (g0 == g7) {
      float v = 0.f;
      #pragma unroll
      for (int r = 0; r < 8; r++) v += lh[r * 64 + t];
      atomicAdd(&sums[g0 * 64 + t], v);
      if (t == 0) atomicAdd(&cnt[g0], 8.f);
    } else {
      for (int r = 0; r < 8; r++) {
        int g = tb[row0 + r];
        atomicAdd(&sums[g * 64 + t], lh[r * 64 + t]);
        if (t == 0) atomicAdd(&cnt[g], 1.f);
      }
    }
  }
}

// value head with fused proc embed (writes out_hp too)
__global__ __launch_bounds__(512) void k_value(const float* __restrict__ tpsum,
    const float* __restrict__ tpcnt, const float* __restrict__ x_proc,
    const float* __restrict__ W_proc, const float* __restrict__ b_proc,
    float* __restrict__ hp_out, const int* __restrict__ pbatch,
    const float* __restrict__ vW1, const float* __restrict__ vb1,
    const float* __restrict__ vW2, const float* __restrict__ vb2,
    float* __restrict__ val_out) {
  __shared__ float ge[8 * 128];
  int t = threadIdx.x;
  int g = t >> 6, d = t & 63;
  float wreg[8];
  #pragma unroll
  for (int k = 0; k < 8; k++) wreg[k] = W_proc[k * 64 + d];
  float bd = b_proc[d];
  for (int p = g; p < 256; p += 8) {
    const float* xr = x_proc + (size_t)p * 8;
    float a = bd;
    #pragma unroll
    for (int k = 0; k < 8; k++) a += xr[k] * wreg[k];
    hp_out[(size_t)p * 64 + d] = a;
  }
  __syncthreads();
  float c = fmaxf(tpcnt[g], 1.f);
  ge[g * 128 + d] = tpsum[g * 64 + d] / c;
  float s = 0.f, cc = 0.f;
  for (int p = 0; p < 256; p++) {
    int bg = pbatch[p];
    if (bg == g) { s += hp_out[(size_t)p * 64 + d]; cc += 1.f; }
  }
  ge[g * 128 + 64 + d] = s / fmaxf(cc, 1.f);
  __syncthreads();
  float acc = vb1[d];
  #pragma unroll 8
  for (int k = 0; k < 128; k++) acc += ge[g * 128 + k] * vW1[k * 64 + d];
  acc = fmaxf(acc, 0.f);
  float p = acc * vW2[d];
  #pragma unroll
  for (int off = 32; off; off >>= 1) p += __shfl_xor(p, off, 64);
  if (d == 0) val_out[g] = p + vb2[0];
}

extern "C" void kernel_launch(void* const* d_in, const int* in_sizes, int n_in,
                              void* d_out, int out_size, void* d_ws, size_t ws_size,
                              hipStream_t stream) {
  (void)in_sizes; (void)n_in; (void)out_size; (void)ws_size;
  const float* x_task  = (const float*)d_in[0];
  const float* x_proc  = (const float*)d_in[1];
  const int*   eidx    = (const int*)d_in[2];
  const float* eattr   = (const float*)d_in[3];
  const int*   tbatch  = (const int*)d_in[4];
  const int*   pbatch  = (const int*)d_in[5];
  const float* W_task  = (const float*)d_in[6];
  const float* b_task  = (const float*)d_in[7];
  const float* W_proc  = (const float*)d_in[8];
  const float* b_proc  = (const float*)d_in[9];
  const float* gat_W   = (const float*)d_in[10];
  const float* gat_We  = (const float*)d_in[11];
  const float* att_src = (const float*)d_in[12];
  const float* att_dst = (const float*)d_in[13];
  const float* att_edge= (const float*)d_in[14];
  const float* gat_b   = (const float*)d_in[15];
  const float* proj_W  = (const float*)d_in[16];
  const float* proj_b  = (const float*)d_in[17];
  const float* ln_g    = (const float*)d_in[18];
  const float* ln_b    = (const float*)d_in[19];
  const float* pt_W1   = (const float*)d_in[20];
  const float* pt_b1   = (const float*)d_in[21];
  const float* pt_W2   = (const float*)d_in[22];
  const float* pt_b2   = (const float*)d_in[23];
  const float* v_W1    = (const float*)d_in[24];
  const float* v_b1    = (const float*)d_in[25];
  const float* v_W2    = (const float*)d_in[26];
  const float* v_b2    = (const float*)d_in[27];

  char* ws = (char*)d_ws;
  int*   deg    = (int*)(ws + OFF_DEG);
  int*   indptr = (int*)(ws + OFF_INDPTR);
  int*   cursor = (int*)(ws + OFF_CURSOR);
  int*   blksum = (int*)(ws + OFF_BLKSUM);
  float* Mg     = (float*)(ws + OFF_MG);
  float* Mh     = (float*)(ws + OFF_MH);
  float* msum   = (float*)(ws + OFF_MEAN);
  float* tpsum  = (float*)(ws + OFF_TPSUM);
  float* tpcnt  = (float*)(ws + OFF_TPCNT);
  uint4* er0    = (uint4*)(ws + OFF_ER0);
  uint4* er1    = (uint4*)(ws + OFF_ER1);
  uint4* er2    = (uint4*)(ws + OFF_ER2);
  float* a_src  = (float*)(ws + OFF_ASRC);
  float* a_dst  = (float*)(ws + OFF_ADST);
  float* ht     = (float*)(ws + OFF_HT);
  __hip_bfloat16* xl  = (__hip_bfloat16*)(ws + OFF_XL);
  __hip_bfloat16* agg = (__hip_bfloat16*)(ws + OFF_AGG);
  __hip_bfloat16* wxf = (__hip_bfloat16*)(ws + OFF_WXF);
  __hip_bfloat16* wpf = (__hip_bfloat16*)(ws + OFF_WPF);
  __hip_bfloat16* wsd = (__hip_bfloat16*)(ws + OFF_WSD);
  uint4* ers[3] = {er0, er1, er2};

  float* out_logits = (float*)d_out;
  float* out_value  = (float*)d_out + NT;
  float* out_ht     = (float*)d_out + NT + NG;
  float* out_hp     = (float*)d_out + NT + NG + (size_t)NT * EMBD;

  hipMemsetAsync(ws + OFF_DEG, 0, NT * 4, stream);
  hipMemsetAsync(ws + OFF_MEAN, 0, 2144, stream);  // msum + tpsum + tpcnt

  k_degree_mean<<<(ET + 255) / 256, 256, 0, stream>>>(eidx + NE, eattr, deg, msum);
  k_scanA<<<NBLK, 1024, 0, stream>>>(deg, indptr, blksum);
  k_scanB<<<NBLK, 1024, 0, stream>>>(blksum, indptr, cursor);
  k_mprep<<<1, 256, 0, stream>>>(gat_We, att_edge, msum, gat_W, att_src, att_dst,
                                 Mg, Mh, wsd);
  k_prep_w<<<192, 64, 0, stream>>>(gat_W, proj_W, wxf, wpf);
  k_fill<<<(ET + 255) / 256, 256, 0, stream>>>(eidx, eidx + NE, eattr, Mg, Mh,
                                               cursor, er0, er1, er2);
  k_embed_xl<<<782, 256, 0, stream>>>(x_task, W_task, b_task, wxf, wsd,
                                      ht, xl, a_src, a_dst);

  for (int l = 0; l < 3; l++) {
    k_attn<<<NT / 4, 256, 0, stream>>>(xl, a_src, a_dst, ers[l], indptr,
                                       gat_b + l * HE, agg);
    if (l < 2) {
      k_proj_xl<<<782, 256, 0, stream>>>(agg, wpf + (size_t)l * 16384,
                                         proj_b + l * EMBD, ln_g + l * EMBD,
                                         ln_b + l * EMBD, ht,
                                         wxf + (size_t)(l + 1) * 16384,
                                         wsd + (size_t)(l + 1) * 1024,
                                         ht, xl, a_src, a_dst);
    } else {
      k_proj_last<<<782, 256, 0, stream>>>(agg, wpf + (size_t)l * 16384,
                                           proj_b + l * EMBD, ln_g + l * EMBD,
                                           ln_b + l * EMBD, ht, out_ht);
    }
  }

  k_task_head<<<NT / 8, 256, 0, stream>>>(out_ht, tbatch, pt_W1, pt_b1, pt_W2, pt_b2,
                                          out_logits, tpsum, tpcnt);
  k_value<<<1, 512, 0, stream>>>(tpsum, tpcnt, x_proc, W_proc, b_proc, out_hp,
                                 pbatch, v_W1, v_b1, v_W2, v_b2, out_value);
}

// Round 11
// 671.947 us; speedup vs baseline: 1.0461x; 1.0461x over previous
//
#include <hip/hip_runtime.h>
#include <hip/hip_bf16.h>
#include <math.h>

#define NT 50000
#define NP 256
#define NE 800000
#define ET 850000   // NE + NT self loops
#define EMBD 64
#define NHEADS 4
#define HE 256      // NHEADS*EMBD
#define NG 8
#define NBLK 49     // scan blocks of 1024

typedef __attribute__((ext_vector_type(8))) short bf16x8;
typedef __attribute__((ext_vector_type(4))) float f32x4;

// ---- workspace layout (bytes) ----
#define OFF_DEG    0u           // 50000 i32
#define OFF_INDPTR 200192u      // 50001 i32
#define OFF_CURSOR 400384u      // 50000 i32
#define OFF_BLKSUM 600576u      // 64 i32
#define OFF_MG     600832u      // 96 f32
#define OFF_MH     601216u      // 12 f32
#define OFF_MEAN   601280u      // 8 f32            <- memset zone start
#define OFF_TPSUM  601344u      // 512 f32
#define OFF_TPCNT  603392u      // 8 f32            <- memset zone end (2144 B)
#define OFF_ER0    603648u      // 850000 uint4 {src, ae01, ae23, 0}
#define OFF_ER1    14203648u
#define OFF_ER2    27803648u
#define OFF_ASRC   41403648u    // 50048*4 f32
#define OFF_ADST   42204416u
#define OFF_HT     43005184u    // 50048*64 f32
#define OFF_XL     55817472u    // 50000*256 bf16
#define OFF_AGG    81417472u    // 50048*256 bf16
#define OFF_WXF    107042048u   // 3*16384 bf16
#define OFF_WPF    107140352u   // 3*16384 bf16
#define OFF_WSD    107238656u   // 3*1024 bf16 (a_src/a_dst MFMA B-tiles)
// total ~107.3 MB

__device__ __forceinline__ float bf_lo(unsigned int u) {
  union { unsigned int i; float f; } v; v.i = u << 16; return v.f;
}
__device__ __forceinline__ float bf_hi(unsigned int u) {
  union { unsigned int i; float f; } v; v.i = u & 0xffff0000u; return v.f;
}
__device__ __forceinline__ unsigned pk2(float a, float b) {
  unsigned ua = __bfloat16_as_ushort(__float2bfloat16(a));
  unsigned ub = __bfloat16_as_ushort(__float2bfloat16(b));
  return ua | (ub << 16);
}

// ---------------- degree + edge_attr mean (fused) ----------------
__global__ __launch_bounds__(256) void k_degree_mean(const int* __restrict__ ei1,
    const float* __restrict__ ea, int* __restrict__ deg, float* __restrict__ sums) {
  __shared__ float lds[256];
  int tid = threadIdx.x;
  int e = blockIdx.x * 256 + tid;
  if (e < ET) {
    int d = (e < NE) ? ei1[e] : (e - NE);
    atomicAdd(&deg[d], 1);
  }
  int k = tid & 7, rl = tid >> 3;
  float s = 0.f;
  for (int row = blockIdx.x * 32 + rl; row < NE; row += gridDim.x * 32)
    s += ea[(size_t)row * 8 + k];
  lds[tid] = s;
  __syncthreads();
  for (int off = 128; off >= 8; off >>= 1) {
    if (tid < off) lds[tid] += lds[tid + off];
    __syncthreads();
  }
  if (tid < 8) atomicAdd(&sums[tid], lds[tid]);
}

// ---------------- parallel scan (2 kernels) ----------------
__global__ __launch_bounds__(1024) void k_scanA(const int* __restrict__ deg,
    int* __restrict__ indptr, int* __restrict__ blksum) {
  __shared__ int wsum[16];
  int tid = threadIdx.x, lane = tid & 63, wid = tid >> 6;
  int i = blockIdx.x * 1024 + tid;
  int v = (i < NT) ? deg[i] : 0;
  int x = v;
  #pragma unroll
  for (int off = 1; off < 64; off <<= 1) {
    int t = __shfl_up(x, off, 64);
    if (lane >= off) x += t;
  }
  if (lane == 63) wsum[wid] = x;
  __syncthreads();
  if (wid == 0 && lane < 16) {
    int w = wsum[lane];
    #pragma unroll
    for (int off = 1; off < 16; off <<= 1) {
      int t = __shfl_up(w, off, 64);
      if (lane >= off) w += t;
    }
    wsum[lane] = w;  // inclusive
  }
  __syncthreads();
  int woff = (wid == 0) ? 0 : wsum[wid - 1];
  if (i < NT) indptr[i] = x + woff - v;   // block-local exclusive
  if (tid == 1023) blksum[blockIdx.x] = wsum[15];
}

__global__ __launch_bounds__(1024) void k_scanB(const int* __restrict__ blksum,
    int* __restrict__ indptr, int* __restrict__ cursor) {
  __shared__ int bs[NBLK];
  int tid = threadIdx.x;
  if (tid < NBLK) bs[tid] = blksum[tid];
  __syncthreads();
  int off = 0;
  for (int j = 0; j < (int)blockIdx.x; j++) off += bs[j];
  int i = blockIdx.x * 1024 + tid;
  if (i < NT) {
    int e = indptr[i] + off;
    indptr[i] = e;
    cursor[i] = e;
  }
  if (blockIdx.x == 0 && tid == 0) {
    int tot = 0;
    for (int j = 0; j < NBLK; j++) tot += bs[j];
    indptr[NT] = tot;
  }
}

// ---------------- M matrices + wsd tiles (all 3 layers) ----------------
__global__ __launch_bounds__(256) void k_mprep(const float* __restrict__ We,
    const float* __restrict__ ae, const float* __restrict__ msum,
    const float* __restrict__ Wx, const float* __restrict__ as_all,
    const float* __restrict__ ad_all,
    float* __restrict__ Mg, float* __restrict__ Mh, __hip_bfloat16* __restrict__ wsd) {
  int t = threadIdx.x;
  if (t < 96) {
    int l = t >> 5, idx = t & 31, k = idx >> 2, h = idx & 3;
    const float* Wl = We + (size_t)l * 8 * HE;
    const float* al = ae + (size_t)l * NHEADS * EMBD;
    float s = 0.f;
    #pragma unroll
    for (int d = 0; d < 64; d++) s += Wl[k * HE + h * 64 + d] * al[h * 64 + d];
    Mg[t] = s;
  }
  __syncthreads();
  if (t < 12) {
    int l = t >> 2, h = t & 3;
    float m = 0.f;
    #pragma unroll
    for (int k = 0; k < 8; k++) m += msum[k] * (1.f / NE) * Mg[l * 32 + k * 4 + h];
    Mh[t] = m;
  }
  for (int v = t; v < 3072; v += 256) {
    int l = v >> 10, rem = v & 1023;
    int kb = rem >> 9, rem2 = rem & 511;
    int lane = rem2 >> 3, j = rem2 & 7;
    int quad = lane >> 4, l15 = lane & 15;
    int k = kb * 32 + quad * 8 + j;
    float val = 0.f;
    if (l15 < 8) {
      int h = l15 & 3;
      const float* av = ((l15 < 4) ? as_all : ad_all) + (size_t)l * NHEADS * EMBD + h * 64;
      const float* Wr = Wx + (size_t)l * 64 * 256 + (size_t)k * 256 + h * 64;
      #pragma unroll
      for (int d = 0; d < 64; d++) val += Wr[d] * av[d];
    }
    wsd[(size_t)l * 1024 + (size_t)(kb * 64 + lane) * 8 + j] = __float2bfloat16(val);
  }
}

// ---------------- CSR fill: packed per-layer records {src, aeh bf16 x4} ----------------
__global__ __launch_bounds__(256) void k_fill(const int* __restrict__ ei0,
    const int* __restrict__ ei1, const float* __restrict__ ea,
    const float* __restrict__ Mg, const float* __restrict__ Mh,
    int* __restrict__ cursor,
    uint4* __restrict__ er0, uint4* __restrict__ er1, uint4* __restrict__ er2) {
  __shared__ float MgS[96];
  __shared__ float MhS[12];
  int t = threadIdx.x;
  if (t < 96) MgS[t] = Mg[t];
  if (t < 12) MhS[t] = Mh[t];
  __syncthreads();
  int e = blockIdx.x * 256 + t;
  if (e >= ET) return;
  int d, s;
  float r[3][4];
  if (e < NE) {
    d = ei1[e]; s = ei0[e];
    const float4* pp = (const float4*)(ea + (size_t)e * 8);
    float4 v0 = pp[0], v1 = pp[1];
    float v[8] = {v0.x, v0.y, v0.z, v0.w, v1.x, v1.y, v1.z, v1.w};
    #pragma unroll
    for (int l = 0; l < 3; l++) {
      #pragma unroll
      for (int h = 0; h < 4; h++) {
        float acc = 0.f;
        #pragma unroll
        for (int k = 0; k < 8; k++) acc += v[k] * MgS[l * 32 + k * 4 + h];
        r[l][h] = acc;
      }
    }
  } else {
    d = e - NE; s = d;
    #pragma unroll
    for (int l = 0; l < 3; l++)
      #pragma unroll
      for (int h = 0; h < 4; h++) r[l][h] = MhS[l * 4 + h];
  }
  int p = atomicAdd(&cursor[d], 1);
  uint4 rc;
  rc.x = (unsigned)s; rc.w = 0u;
  rc.y = pk2(r[0][0], r[0][1]); rc.z = pk2(r[0][2], r[0][3]); er0[p] = rc;
  rc.y = pk2(r[1][0], r[1][1]); rc.z = pk2(r[1][2], r[1][3]); er1[p] = rc;
  rc.y = pk2(r[2][0], r[2][1]); rc.z = pk2(r[2][2], r[2][3]); er2[p] = rc;
}

// ---------------- weight fragment prep (fused xl+proj) ----------------
__global__ void k_prep_w(const float* __restrict__ Wx, const float* __restrict__ Wp,
                         __hip_bfloat16* __restrict__ Wxf, __hip_bfloat16* __restrict__ Wpf) {
  int lane = threadIdx.x;
  int bid = blockIdx.x;
  int quad = lane >> 4, l15 = lane & 15;
  if (bid < 96) {
    int l = bid >> 5, rem = bid & 31, t = rem >> 1, kb = rem & 1;
    const float* Wl = Wx + (size_t)l * 64 * 256;
    __hip_bfloat16* out = Wxf + (size_t)l * 16384 + (size_t)((t * 2 + kb) * 64 + lane) * 8;
    #pragma unroll
    for (int j = 0; j < 8; j++)
      out[j] = __float2bfloat16(Wl[(kb * 32 + quad * 8 + j) * 256 + t * 16 + l15]);
  } else {
    bid -= 96;
    int l = bid >> 5, rem = bid & 31, t = rem >> 3, kb = rem & 7;
    const float* Wl = Wp + (size_t)l * 256 * 64;
    __hip_bfloat16* out = Wpf + (size_t)l * 16384 + (size_t)((t * 8 + kb) * 64 + lane) * 8;
    #pragma unroll
    for (int j = 0; j < 8; j++)
      out[j] = __float2bfloat16(Wl[(kb * 32 + quad * 8 + j) * 64 + t * 16 + l15]);
  }
}

// ---------------- fused embed + xl(0) + a_src/a_dst(0) ----------------
__global__ __launch_bounds__(256) void k_embed_xl(const float* __restrict__ x,
    const float* __restrict__ W, const float* __restrict__ b,
    const __hip_bfloat16* __restrict__ Wf, const __hip_bfloat16* __restrict__ wsd,
    float* __restrict__ ht, __hip_bfloat16* __restrict__ xl,
    float* __restrict__ a_src, float* __restrict__ a_dst) {
  __shared__ __hip_bfloat16 hbuf[64 * 72];
  __shared__ __hip_bfloat16 cb16[64 * 264];
  int tid = threadIdx.x, lane = tid & 63, wave = tid >> 6;
  int quad = lane >> 4, l15 = lane & 15;
  int r0 = blockIdx.x * 64;
  {
    float breg[16];
    #pragma unroll
    for (int k = 0; k < 16; k++) breg[k] = W[k * 64 + lane];
    float bias = b[lane];
    #pragma unroll 1
    for (int rr = 0; rr < 16; rr++) {
      int row = r0 + wave * 16 + rr;
      float acc = bias;
      if (row < NT) {
        const float4* xr = (const float4*)(x + (size_t)row * 16);
        #pragma unroll
        for (int q = 0; q < 4; q++) {
          float4 v = xr[q];
          acc += v.x * breg[q*4+0] + v.y * breg[q*4+1] + v.z * breg[q*4+2] + v.w * breg[q*4+3];
        }
        ht[(size_t)row * 64 + lane] = acc;
      }
      hbuf[(wave * 16 + rr) * 72 + lane] = __float2bfloat16(acc);
    }
  }
  __syncthreads();
  f32x4 acc[16], accE;
  #pragma unroll
  for (int t = 0; t < 16; t++) acc[t] = (f32x4){0.f, 0.f, 0.f, 0.f};
  accE = (f32x4){0.f, 0.f, 0.f, 0.f};
  #pragma unroll
  for (int kb = 0; kb < 2; kb++) {
    bf16x8 a = *(const bf16x8*)(&hbuf[(wave * 16 + l15) * 72 + kb * 32 + quad * 8]);
    #pragma unroll
    for (int t = 0; t < 16; t++) {
      bf16x8 bfr = *(const bf16x8*)(Wf + (size_t)((t * 2 + kb) * 64 + lane) * 8);
      acc[t] = __builtin_amdgcn_mfma_f32_16x16x32_bf16(a, bfr, acc[t], 0, 0, 0);
    }
    bf16x8 bs = *(const bf16x8*)(wsd + (size_t)(kb * 64 + lane) * 8);
    accE = __builtin_amdgcn_mfma_f32_16x16x32_bf16(a, bs, accE, 0, 0, 0);
  }
  int rloc = wave * 16 + quad * 4;
  #pragma unroll
  for (int t = 0; t < 16; t++) {
    #pragma unroll
    for (int reg = 0; reg < 4; reg++)
      cb16[(rloc + reg) * 264 + t * 16 + l15] = __float2bfloat16(acc[t][reg]);
  }
  #pragma unroll
  for (int reg = 0; reg < 4; reg++) {
    int row = r0 + rloc + reg;
    if (l15 < 8 && row < NT) {
      float* dst = (l15 < 4) ? a_src : a_dst;
      dst[row * 4 + (l15 & 3)] = accE[reg];
    }
  }
  __syncthreads();
  #pragma unroll
  for (int k = 0; k < 8; k++) {
    int c = k * 256 + tid;
    int row = c >> 5, off = c & 31;
    if (r0 + row < NT) {
      uint4 v = *(const uint4*)(&cb16[row * 264 + off * 8]);
      *(uint4*)(xl + (size_t)(r0 + row) * HE + off * 8) = v;
    }
  }
}

// ---------------- fused softmax + aggregate (no-max softmax, batched gathers) ----------------
__global__ __launch_bounds__(256) void k_attn(
    const __hip_bfloat16* __restrict__ xl, const float* __restrict__ a_src,
    const float* __restrict__ a_dst, const uint4* __restrict__ er,
    const int* __restrict__ indptr, const float* __restrict__ gb,
    __hip_bfloat16* __restrict__ agg) {
  int node = blockIdx.x * 4 + (threadIdx.x >> 6);
  int lane = threadIdx.x & 63;
  int h = lane >> 4;
  int hbase = lane & 48;
  int e15 = lane & 15;
  int beg = indptr[node], end = indptr[node + 1];
  float adh = a_dst[node * 4 + h];
  float S = 0.f;
  float acc0 = 0.f, acc1 = 0.f, acc2 = 0.f, acc3 = 0.f;
  for (int base = beg; base < end; base += 16) {
    int cnt = end - base;           // >=1
    bool ok = e15 < cnt;
    uint4 rec; rec.x = 0u; rec.y = 0u; rec.z = 0u; rec.w = 0u;
    if (ok) rec = er[base + e15];
    int my_src = (int)rec.x;
    unsigned wsel = (h < 2) ? rec.y : rec.z;
    float aeh = (h & 1) ? bf_hi(wsel) : bf_lo(wsel);
    float asr = ok ? a_src[(size_t)my_src * 4 + h] : 0.f;
    float al = asr + adh + aeh;
    al = (al > 0.f) ? al : 0.2f * al;
    float ex = ok ? __expf(al) : 0.f;   // no max-shift: al bounded (range analysis R9)
    S += ex;
    #pragma unroll
    for (int jb = 0; jb < 2; jb++) {
      int sr[8];
      #pragma unroll
      for (int j = 0; j < 8; j++) sr[j] = __shfl(my_src, jb * 8 + j, 64);
      uint2 u[8];
      #pragma unroll
      for (int j = 0; j < 8; j++)
        u[j] = *(const uint2*)(xl + (size_t)sr[j] * HE + lane * 4);
      #pragma unroll
      for (int j = 0; j < 8; j++) {
        float cf = __shfl(ex, hbase | (jb * 8 + j), 64);
        acc0 += cf * bf_lo(u[j].x);
        acc1 += cf * bf_hi(u[j].x);
        acc2 += cf * bf_lo(u[j].y);
        acc3 += cf * bf_hi(u[j].y);
      }
    }
  }
  #pragma unroll
  for (int off = 1; off < 16; off <<= 1) S += __shfl_xor(S, off, 64);
  float inv = 1.f / (S + 1e-16f);
  float4 g4 = *(const float4*)(gb + lane * 4);
  unsigned int o0 = __bfloat16_as_ushort(__float2bfloat16(acc0 * inv + g4.x));
  unsigned int o1 = __bfloat16_as_ushort(__float2bfloat16(acc1 * inv + g4.y));
  unsigned int o2 = __bfloat16_as_ushort(__float2bfloat16(acc2 * inv + g4.z));
  unsigned int o3 = __bfloat16_as_ushort(__float2bfloat16(acc3 * inv + g4.w));
  uint2 out; out.x = o0 | (o1 << 16); out.y = o2 | (o3 << 16);
  *(uint2*)(agg + (size_t)node * HE + lane * 4) = out;
}

// ---------------- fused proj + LN + next-layer xl + a_src/a_dst ----------------
__global__ __launch_bounds__(256) void k_proj_xl(
    const __hip_bfloat16* __restrict__ agg, const __hip_bfloat16* __restrict__ Wpf,
    const float* __restrict__ pb, const float* __restrict__ g, const float* __restrict__ bln,
    const float* __restrict__ ht_io,
    const __hip_bfloat16* __restrict__ Wxf, const __hip_bfloat16* __restrict__ wsd,
    float* __restrict__ ht_out, __hip_bfloat16* __restrict__ xl,
    float* __restrict__ a_src, float* __restrict__ a_dst) {
  __shared__ __hip_bfloat16 cb16[64 * 264];   // also used as f32 cbuf (pitch 68)
  __shared__ __hip_bfloat16 hbuf[64 * 72];
  __shared__ float pbL[64], gL[64], bL[64];
  float* cbf = (float*)cb16;
  int tid = threadIdx.x, lane = tid & 63, wave = tid >> 6;
  int quad = lane >> 4, l15 = lane & 15;
  if (tid < 64) { pbL[tid] = pb[tid]; gL[tid] = g[tid]; bL[tid] = bln[tid]; }
  int r0 = blockIdx.x * 64;
  int arow = r0 + wave * 16 + l15;
  {
    f32x4 pacc[4];
    #pragma unroll
    for (int t = 0; t < 4; t++) pacc[t] = (f32x4){0.f, 0.f, 0.f, 0.f};
    #pragma unroll
    for (int kb = 0; kb < 8; kb++) {
      bf16x8 a = *(const bf16x8*)(agg + (size_t)arow * HE + kb * 32 + quad * 8);
      #pragma unroll
      for (int t = 0; t < 4; t++) {
        bf16x8 bfr = *(const bf16x8*)(Wpf + (size_t)((t * 8 + kb) * 64 + lane) * 8);
        pacc[t] = __builtin_amdgcn_mfma_f32_16x16x32_bf16(a, bfr, pacc[t], 0, 0, 0);
      }
    }
    int rloc = wave * 16 + quad * 4;
    #pragma unroll
    for (int t = 0; t < 4; t++) {
      #pragma unroll
      for (int reg = 0; reg < 4; reg++)
        cbf[(rloc + reg) * 68 + t * 16 + l15] = pacc[t][reg];
    }
  }
  __syncthreads();
  {
    int r = tid >> 2, q = tid & 3;
    int row = r0 + r;
    float h[16], s1 = 0.f, s2 = 0.f;
    const float* hin = ht_io + (size_t)row * 64 + q * 16;
    #pragma unroll
    for (int d = 0; d < 16; d++) {
      float u = cbf[r * 68 + q * 16 + d] + pbL[q * 16 + d];
      u = (u > 0.f) ? u : (__expf(u) - 1.f);
      float hv = hin[d] + u;
      h[d] = hv;
      s1 += hv; s2 += hv * hv;
    }
    s1 += __shfl_xor(s1, 1, 64); s1 += __shfl_xor(s1, 2, 64);
    s2 += __shfl_xor(s2, 1, 64); s2 += __shfl_xor(s2, 2, 64);
    float mu = s1 * 0.015625f;
    float var = s2 * 0.015625f - mu * mu;
    float rstd = rsqrtf(var + 1e-5f);
    float o[16];
    #pragma unroll
    for (int d = 0; d < 16; d++)
      o[d] = (h[d] - mu) * rstd * gL[q * 16 + d] + bL[q * 16 + d];
    if (row < NT) {
      float* outp = ht_out + (size_t)row * 64 + q * 16;
      #pragma unroll
      for (int d4 = 0; d4 < 4; d4++) {
        float4 v; v.x = o[d4*4]; v.y = o[d4*4+1]; v.z = o[d4*4+2]; v.w = o[d4*4+3];
        *(float4*)(outp + d4 * 4) = v;
      }
    }
    uint4 u0, u1;
    u0.x = pk2(o[0], o[1]);  u0.y = pk2(o[2], o[3]);
    u0.z = pk2(o[4], o[5]);  u0.w = pk2(o[6], o[7]);
    u1.x = pk2(o[8], o[9]);  u1.y = pk2(o[10], o[11]);
    u1.z = pk2(o[12], o[13]); u1.w = pk2(o[14], o[15]);
    uint4* hb = (uint4*)(&hbuf[r * 72 + q * 16]);
    hb[0] = u0; hb[1] = u1;
  }
  __syncthreads();
  f32x4 acc[16], accE;
  #pragma unroll
  for (int t = 0; t < 16; t++) acc[t] = (f32x4){0.f, 0.f, 0.f, 0.f};
  accE = (f32x4){0.f, 0.f, 0.f, 0.f};
  #pragma unroll
  for (int kb = 0; kb < 2; kb++) {
    bf16x8 a = *(const bf16x8*)(&hbuf[(wave * 16 + l15) * 72 + kb * 32 + quad * 8]);
    #pragma unroll
    for (int t = 0; t < 16; t++) {
      bf16x8 bfr = *(const bf16x8*)(Wxf + (size_t)((t * 2 + kb) * 64 + lane) * 8);
      acc[t] = __builtin_amdgcn_mfma_f32_16x16x32_bf16(a, bfr, acc[t], 0, 0, 0);
    }
    bf16x8 bs = *(const bf16x8*)(wsd + (size_t)(kb * 64 + lane) * 8);
    accE = __builtin_amdgcn_mfma_f32_16x16x32_bf16(a, bs, accE, 0, 0, 0);
  }
  int rloc = wave * 16 + quad * 4;
  #pragma unroll
  for (int t = 0; t < 16; t++) {
    #pragma unroll
    for (int reg = 0; reg < 4; reg++)
      cb16[(rloc + reg) * 264 + t * 16 + l15] = __float2bfloat16(acc[t][reg]);
  }
  #pragma unroll
  for (int reg = 0; reg < 4; reg++) {
    int row = r0 + rloc + reg;
    if (l15 < 8 && row < NT) {
      float* dst = (l15 < 4) ? a_src : a_dst;
      dst[row * 4 + (l15 & 3)] = accE[reg];
    }
  }
  __syncthreads();
  #pragma unroll
  for (int k = 0; k < 8; k++) {
    int c = k * 256 + tid;
    int row = c >> 5, off = c & 31;
    if (r0 + row < NT) {
      uint4 v = *(const uint4*)(&cb16[row * 264 + off * 8]);
      *(uint4*)(xl + (size_t)(r0 + row) * HE + off * 8) = v;
    }
  }
}

// ---------------- last-layer proj + LN (writes out_ht only) ----------------
__global__ __launch_bounds__(256) void k_proj_last(
    const __hip_bfloat16* __restrict__ agg, const __hip_bfloat16* __restrict__ Wpf,
    const float* __restrict__ pb, const float* __restrict__ g, const float* __restrict__ bln,
    const float* __restrict__ ht_in, float* __restrict__ ht_out) {
  __shared__ float cbf[64 * 68];
  __shared__ float pbL[64], gL[64], bL[64];
  int tid = threadIdx.x, lane = tid & 63, wave = tid >> 6;
  int quad = lane >> 4, l15 = lane & 15;
  if (tid < 64) { pbL[tid] = pb[tid]; gL[tid] = g[tid]; bL[tid] = bln[tid]; }
  int r0 = blockIdx.x * 64;
  int arow = r0 + wave * 16 + l15;
  f32x4 pacc[4];
  #pragma unroll
  for (int t = 0; t < 4; t++) pacc[t] = (f32x4){0.f, 0.f, 0.f, 0.f};
  #pragma unroll
  for (int kb = 0; kb < 8; kb++) {
    bf16x8 a = *(const bf16x8*)(agg + (size_t)arow * HE + kb * 32 + quad * 8);
    #pragma unroll
    for (int t = 0; t < 4; t++) {
      bf16x8 bfr = *(const bf16x8*)(Wpf + (size_t)((t * 8 + kb) * 64 + lane) * 8);
      pacc[t] = __builtin_amdgcn_mfma_f32_16x16x32_bf16(a, bfr, pacc[t], 0, 0, 0);
    }
  }
  int rloc = wave * 16 + quad * 4;
  #pragma unroll
  for (int t = 0; t < 4; t++) {
    #pragma unroll
    for (int reg = 0; reg < 4; reg++)
      cbf[(rloc + reg) * 68 + t * 16 + l15] = pacc[t][reg];
  }
  __syncthreads();
  int r = tid >> 2, q = tid & 3;
  int row = r0 + r;
  float h[16], s1 = 0.f, s2 = 0.f;
  const float* hin = ht_in + (size_t)row * 64 + q * 16;
  #pragma unroll
  for (int d = 0; d < 16; d++) {
    float u = cbf[r * 68 + q * 16 + d] + pbL[q * 16 + d];
    u = (u > 0.f) ? u : (__expf(u) - 1.f);
    float hv = hin[d] + u;
    h[d] = hv;
    s1 += hv; s2 += hv * hv;
  }
  s1 += __shfl_xor(s1, 1, 64); s1 += __shfl_xor(s1, 2, 64);
  s2 += __shfl_xor(s2, 1, 64); s2 += __shfl_xor(s2, 2, 64);
  float mu = s1 * 0.015625f;
  float var = s2 * 0.015625f - mu * mu;
  float rstd = rsqrtf(var + 1e-5f);
  if (row < NT) {
    float* outp = ht_out + (size_t)row * 64 + q * 16;
    #pragma unroll
    for (int d4 = 0; d4 < 4; d4++) {
      float4 v;
      v.x = (h[d4*4+0] - mu) * rstd * gL[q*16+d4*4+0] + bL[q*16+d4*4+0];
      v.y = (h[d4*4+1] - mu) * rstd * gL[q*16+d4*4+1] + bL[q*16+d4*4+1];
      v.z = (h[d4*4+2] - mu) * rstd * gL[q*16+d4*4+2] + bL[q*16+d4*4+2];
      v.w = (h[d4*4+3] - mu) * rstd * gL[q*16+d4*4+3] + bL[q*16+d4*4+3];
      *(float4*)(outp + d4 * 4) = v;
    }
  }
}

// ---------------- heads ----------------
__global__ __launch_bounds__(256) void k_task_head(const float* __restrict__ ht,
    const float* __restrict__ W1, const float* __restrict__ b1,
    const float* __restrict__ W2, const float* __restrict__ b2, float* __restrict__ logits) {
  __shared__ float lh[8 * 64];
  int t = threadIdx.x;
  size_t base = (size_t)blockIdx.x * 8 * 64;
  lh[t] = ht[base + t];
  lh[t + 256] = ht[base + t + 256];
  __syncthreads();
  int i = t >> 5, j = t & 31;
  float s = b1[j];
  #pragma unroll 8
  for (int d = 0; d < 64; d++) s += lh[i * 64 + d] * W1[d * 32 + j];
  s = fmaxf(s, 0.f);
  float p = s * W2[j];
  #pragma unroll
  for (int off = 16; off; off >>= 1) p += __shfl_xor(p, off, 64);
  if (j == 0) logits[blockIdx.x * 8 + i] = p + b2[0];
}

__global__ __launch_bounds__(256) void k_pool_task(const float* __restrict__ ht,
    const int* __restrict__ tb, float* __restrict__ sums, float* __restrict__ cnt) {
  int lane = threadIdx.x & 63, sub = threadIdx.x >> 6;
  float acc[8], c[8];
  #pragma unroll
  for (int g = 0; g < 8; g++) { acc[g] = 0.f; c[g] = 0.f; }
  int lim = min(NT, (int)((blockIdx.x + 1) * 512));
  for (int n = blockIdx.x * 512 + sub; n < lim; n += 4) {
    int g = tb[n];
    float v = ht[(size_t)n * 64 + lane];
    #pragma unroll
    for (int gg = 0; gg < 8; gg++) {
      if (g == gg) { acc[gg] += v; c[gg] += 1.f; }
    }
  }
  #pragma unroll
  for (int g = 0; g < 8; g++) {
    if (__any(acc[g] != 0.f || c[g] != 0.f)) {
      atomicAdd(&sums[g * 64 + lane], acc[g]);
      if (lane == 0) atomicAdd(&cnt[g], c[g]);
    }
  }
}

// value head with fused proc embed (writes out_hp too)
__global__ __launch_bounds__(512) void k_value(const float* __restrict__ tpsum,
    const float* __restrict__ tpcnt, const float* __restrict__ x_proc,
    const float* __restrict__ W_proc, const float* __restrict__ b_proc,
    float* __restrict__ hp_out, const int* __restrict__ pbatch,
    const float* __restrict__ vW1, const float* __restrict__ vb1,
    const float* __restrict__ vW2, const float* __restrict__ vb2,
    float* __restrict__ val_out) {
  __shared__ float ge[8 * 128];
  int t = threadIdx.x;
  int g = t >> 6, d = t & 63;
  float wreg[8];
  #pragma unroll
  for (int k = 0; k < 8; k++) wreg[k] = W_proc[k * 64 + d];
  float bd = b_proc[d];
  for (int p = g; p < 256; p += 8) {
    const float* xr = x_proc + (size_t)p * 8;
    float a = bd;
    #pragma unroll
    for (int k = 0; k < 8; k++) a += xr[k] * wreg[k];
    hp_out[(size_t)p * 64 + d] = a;
  }
  __syncthreads();
  float c = fmaxf(tpcnt[g], 1.f);
  ge[g * 128 + d] = tpsum[g * 64 + d] / c;
  float s = 0.f, cc = 0.f;
  for (int p = 0; p < 256; p++) {
    int bg = pbatch[p];
    if (bg == g) { s += hp_out[(size_t)p * 64 + d]; cc += 1.f; }
  }
  ge[g * 128 + 64 + d] = s / fmaxf(cc, 1.f);
  __syncthreads();
  float acc = vb1[d];
  #pragma unroll 8
  for (int k = 0; k < 128; k++) acc += ge[g * 128 + k] * vW1[k * 64 + d];
  acc = fmaxf(acc, 0.f);
  float p = acc * vW2[d];
  #pragma unroll
  for (int off = 32; off; off >>= 1) p += __shfl_xor(p, off, 64);
  if (d == 0) val_out[g] = p + vb2[0];
}

extern "C" void kernel_launch(void* const* d_in, const int* in_sizes, int n_in,
                              void* d_out, int out_size, void* d_ws, size_t ws_size,
                              hipStream_t stream) {
  (void)in_sizes; (void)n_in; (void)out_size; (void)ws_size;
  const float* x_task  = (const float*)d_in[0];
  const float* x_proc  = (const float*)d_in[1];
  const int*   eidx    = (const int*)d_in[2];
  const float* eattr   = (const float*)d_in[3];
  const int*   tbatch  = (const int*)d_in[4];
  const int*   pbatch  = (const int*)d_in[5];
  const float* W_task  = (const float*)d_in[6];
  const float* b_task  = (const float*)d_in[7];
  const float* W_proc  = (const float*)d_in[8];
  const float* b_proc  = (const float*)d_in[9];
  const float* gat_W   = (const float*)d_in[10];
  const float* gat_We  = (const float*)d_in[11];
  const float* att_src = (const float*)d_in[12];
  const float* att_dst = (const float*)d_in[13];
  const float* att_edge= (const float*)d_in[14];
  const float* gat_b   = (const float*)d_in[15];
  const float* proj_W  = (const float*)d_in[16];
  const float* proj_b  = (const float*)d_in[17];
  const float* ln_g    = (const float*)d_in[18];
  const float* ln_b    = (const float*)d_in[19];
  const float* pt_W1   = (const float*)d_in[20];
  const float* pt_b1   = (const float*)d_in[21];
  const float* pt_W2   = (const float*)d_in[22];
  const float* pt_b2   = (const float*)d_in[23];
  const float* v_W1    = (const float*)d_in[24];
  const float* v_b1    = (const float*)d_in[25];
  const float* v_W2    = (const float*)d_in[26];
  const float* v_b2    = (const float*)d_in[27];

  char* ws = (char*)d_ws;
  int*   deg    = (int*)(ws + OFF_DEG);
  int*   indptr = (int*)(ws + OFF_INDPTR);
  int*   cursor = (int*)(ws + OFF_CURSOR);
  int*   blksum = (int*)(ws + OFF_BLKSUM);
  float* Mg     = (float*)(ws + OFF_MG);
  float* Mh     = (float*)(ws + OFF_MH);
  float* msum   = (float*)(ws + OFF_MEAN);
  float* tpsum  = (float*)(ws + OFF_TPSUM);
  float* tpcnt  = (float*)(ws + OFF_TPCNT);
  uint4* er0    = (uint4*)(ws + OFF_ER0);
  uint4* er1    = (uint4*)(ws + OFF_ER1);
  uint4* er2    = (uint4*)(ws + OFF_ER2);
  float* a_src  = (float*)(ws + OFF_ASRC);
  float* a_dst  = (float*)(ws + OFF_ADST);
  float* ht     = (float*)(ws + OFF_HT);
  __hip_bfloat16* xl  = (__hip_bfloat16*)(ws + OFF_XL);
  __hip_bfloat16* agg = (__hip_bfloat16*)(ws + OFF_AGG);
  __hip_bfloat16* wxf = (__hip_bfloat16*)(ws + OFF_WXF);
  __hip_bfloat16* wpf = (__hip_bfloat16*)(ws + OFF_WPF);
  __hip_bfloat16* wsd = (__hip_bfloat16*)(ws + OFF_WSD);
  uint4* ers[3] = {er0, er1, er2};

  float* out_logits = (float*)d_out;
  float* out_value  = (float*)d_out + NT;
  float* out_ht     = (float*)d_out + NT + NG;
  float* out_hp     = (float*)d_out + NT + NG + (size_t)NT * EMBD;

  hipMemsetAsync(ws + OFF_DEG, 0, NT * 4, stream);
  hipMemsetAsync(ws + OFF_MEAN, 0, 2144, stream);  // msum + tpsum + tpcnt

  k_degree_mean<<<(ET + 255) / 256, 256, 0, stream>>>(eidx + NE, eattr, deg, msum);
  k_scanA<<<NBLK, 1024, 0, stream>>>(deg, indptr, blksum);
  k_scanB<<<NBLK, 1024, 0, stream>>>(blksum, indptr, cursor);
  k_mprep<<<1, 256, 0, stream>>>(gat_We, att_edge, msum, gat_W, att_src, att_dst,
                                 Mg, Mh, wsd);
  k_prep_w<<<192, 64, 0, stream>>>(gat_W, proj_W, wxf, wpf);
  k_fill<<<(ET + 255) / 256, 256, 0, stream>>>(eidx, eidx + NE, eattr, Mg, Mh,
                                               cursor, er0, er1, er2);
  k_embed_xl<<<782, 256, 0, stream>>>(x_task, W_task, b_task, wxf, wsd,
                                      ht, xl, a_src, a_dst);

  for (int l = 0; l < 3; l++) {
    k_attn<<<NT / 4, 256, 0, stream>>>(xl, a_src, a_dst, ers[l], indptr,
                                       gat_b + l * HE, agg);
    if (l < 2) {
      k_proj_xl<<<782, 256, 0, stream>>>(agg, wpf + (size_t)l * 16384,
                                         proj_b + l * EMBD, ln_g + l * EMBD,
                                         ln_b + l * EMBD, ht,
                                         wxf + (size_t)(l + 1) * 16384,
                                         wsd + (size_t)(l + 1) * 1024,
                                         ht, xl, a_src, a_dst);
    } else {
      k_proj_last<<<782, 256, 0, stream>>>(agg, wpf + (size_t)l * 16384,
                                           proj_b + l * EMBD, ln_g + l * EMBD,
                                           ln_b + l * EMBD, ht, out_ht);
    }
  }

  k_task_head<<<NT / 8, 256, 0, stream>>>(out_ht, pt_W1, pt_b1, pt_W2, pt_b2, out_logits);
  k_pool_task<<<(NT + 511) / 512, 256, 0, stream>>>(out_ht, tbatch, tpsum, tpcnt);
  k_value<<<1, 512, 0, stream>>>(tpsum, tpcnt, x_proc, W_proc, b_proc, out_hp,
                                 pbatch, v_W1, v_b1, v_W2, v_b2, out_value);
}